// Round 6
// baseline (61.509 us; speedup 1.0000x reference)
//
#include <hip/hip_runtime.h>

typedef unsigned int u32;
typedef unsigned short u16;
typedef __attribute__((ext_vector_type(8))) _Float16 f16x8;
typedef __attribute__((ext_vector_type(4))) float f32x4;

namespace {

constexpr int kH = 48, kW = 48, kHW = kH * kW;     // 2304
constexpr int kC = 256;
constexpr int kB = 2;
constexpr int kM = kB * kHW;                        // 4608 GEMM rows
constexpr int kPH = 54, kPW = 56, kPP = kPH * kPW;  // padded kv grid (3024)
constexpr float kInvTemp = 0.17677669529663687f;    // 1/sqrt(32)

constexpr size_t KPAD_U16 = (size_t)16 * kPP * 32;  // 1,548,288 u16 per mat
constexpr size_t QBF_U16 = (size_t)kM * kC;         // 1,179,648 u16
// border zeroing: 720 border pixels/plane x 16 planes x 2 mats x 4 uint4
constexpr int kZeroTasks = 720 * 16 * 2 * 4;        // 92,160
constexpr int kZeroPerBlk = 427;                    // 216 qkv blocks x 427 >= 92160

// 1-instruction f32x2 -> f16x2 pack (v_cvt_pkrtz_f16_f32)
__device__ __forceinline__ u32 pack2h(float lo, float hi) {
  return __builtin_bit_cast(u32, __builtin_amdgcn_cvt_pkrtz(lo, hi));
}
__device__ __forceinline__ u16 f2h(float f) {
  return __builtin_bit_cast(u16, (_Float16)f);
}
__device__ __forceinline__ float f4e(const float4 v, int i) {
  return (i == 0) ? v.x : (i == 1) ? v.y : (i == 2) ? v.z : v.w;
}

// ---------------------------------------------------------------------------
// Fused QKV GEMM, 128x128 tiles (halves operand re-read traffic vs 64x64).
// A staged directly from fp32 [b][c][p] (register 4x4 transpose + pkrtz).
// z=0: q -> f16 [m][256].  z=1/2: k/v -> zero-padded f16 [bh][54*56][32].
// Also zeroes the pad borders (disjoint from interior epilogue writes).
// ---------------------------------------------------------------------------
__global__ __launch_bounds__(256) void gemm_qkv_kernel(
    const float* __restrict__ q, const float* __restrict__ k,
    const float* __restrict__ v, const float* __restrict__ Wq,
    const float* __restrict__ Wk, const float* __restrict__ Wv,
    u16* __restrict__ qbf, u16* __restrict__ kpad, u16* __restrict__ vpad) {
  __shared__ __align__(16) u16 As[128 * 64];
  __shared__ __align__(16) u16 Bs[128 * 64];
  const int t = threadIdx.x;

  // ---- border zeroing (1.5 MB total across the 216 blocks) ----
  {
    const int bid = (blockIdx.z * 2 + blockIdx.y) * 36 + blockIdx.x;
#pragma unroll
    for (int i = 0; i < 2; ++i) {
      const int tt = t + i * 256;
      if (tt < kZeroPerBlk) {
        const int T = bid * kZeroPerBlk + tt;
        if (T < kZeroTasks) {
          const int ch = T & 3, rest = T >> 2;  // rest < 23040
          const int pm = rest / 720, bi = rest - pm * 720;
          int y, x;
          if (bi < 336) {  // full rows 0,1,2,51,52,53
            const int r = bi / 56, c = bi - (bi / 56) * 56;
            y = (r < 3) ? r : 48 + r;
            x = c;
          } else {  // rows 3..50, cols {0,1,2,51..55}
            const int r = (bi - 336) >> 3, c = (bi - 336) & 7;
            y = 3 + r;
            x = (c < 3) ? c : c + 48;
          }
          u16* pb = (pm >= 16) ? vpad : kpad;
          const uint4 zz = {0u, 0u, 0u, 0u};
          *(uint4*)&pb[((size_t)(pm & 15) * kPP + y * kPW + x) * 32 + ch * 8] =
              zz;
        }
      }
    }
  }

  const int z = blockIdx.z;
  const float* X = (z == 0) ? q : (z == 1) ? k : v;
  const float* Wm = (z == 0) ? Wq : (z == 1) ? Wk : Wv;
  const int m0 = blockIdx.x * 128, n0 = blockIdx.y * 128;
  const int bb = m0 / kHW, p0 = m0 - bb * kHW;  // 2304%128==0: no straddle
  const int l = t & 63, w = t >> 6, wm = w >> 1, wn = w & 1;
  const int mq = t & 31, kq = t >> 5;

  f32x4 acc[4][4];
#pragma unroll
  for (int mf = 0; mf < 4; ++mf)
#pragma unroll
    for (int nf = 0; nf < 4; ++nf) acc[mf][nf] = (f32x4){0.f, 0.f, 0.f, 0.f};

  for (int kt = 0; kt < 4; ++kt) {
    const int k0 = kt * 64;
    if (kt) __syncthreads();
    // A stage: 2 passes x (4 coalesced c-row float4 reads, 4x4 register
    // transpose, pkrtz pack, 8B swizzled LDS writes).
#pragma unroll
    for (int i2 = 0; i2 < 2; ++i2) {
      const float* ab =
          X + ((size_t)(bb * kC + k0 + i2 * 32 + kq * 4)) * kHW + p0 + mq * 4;
      const float4 r0 = *(const float4*)(ab);
      const float4 r1 = *(const float4*)(ab + kHW);
      const float4 r2 = *(const float4*)(ab + 2 * kHW);
      const float4 r3 = *(const float4*)(ab + 3 * kHW);
#pragma unroll
      for (int i = 0; i < 4; ++i) {
        const int ml = mq * 4 + i;
        uint2 pk;
        pk.x = pack2h(f4e(r0, i), f4e(r1, i));
        pk.y = pack2h(f4e(r2, i), f4e(r3, i));
        const int bo = (i2 * 64 + kq * 8) ^ ((ml & 7) << 4);
        *(uint2*)&As[ml * 64 + (bo >> 1)] = pk;
      }
    }
    // B stage: fp32 W[o][c] -> f16, same swizzle (128 rows x 16 float4)
#pragma unroll
    for (int j = 0; j < 8; ++j) {
      const int task = t + j * 256;
      const int rr = task >> 4, f4i = task & 15;
      const float4 val =
          *(const float4*)&Wm[(size_t)(n0 + rr) * kC + k0 + f4i * 4];
      uint2 pk;
      pk.x = pack2h(val.x, val.y);
      pk.y = pack2h(val.z, val.w);
      const int bo = (f4i * 8) ^ ((rr & 7) << 4);
      *(uint2*)&Bs[rr * 64 + (bo >> 1)] = pk;
    }
    __syncthreads();
#pragma unroll
    for (int ks = 0; ks < 2; ++ks) {
      const int bo = ks * 64 + ((l >> 4) << 4);
      f16x8 a[4], bfr[4];
#pragma unroll
      for (int mf = 0; mf < 4; ++mf) {
        const int row = wm * 64 + mf * 16 + (l & 15);
        a[mf] = *(const f16x8*)&As[row * 64 + ((bo ^ ((row & 7) << 4)) >> 1)];
      }
#pragma unroll
      for (int nf = 0; nf < 4; ++nf) {
        const int row = wn * 64 + nf * 16 + (l & 15);
        bfr[nf] =
            *(const f16x8*)&Bs[row * 64 + ((bo ^ ((row & 7) << 4)) >> 1)];
      }
#pragma unroll
      for (int mf = 0; mf < 4; ++mf)
#pragma unroll
        for (int nf = 0; nf < 4; ++nf)
          acc[mf][nf] = __builtin_amdgcn_mfma_f32_16x16x32_f16(
              a[mf], bfr[nf], acc[mf][nf], 0, 0, 0);
    }
  }

  u16* pd = (z == 1) ? kpad : vpad;
#pragma unroll
  for (int mf = 0; mf < 4; ++mf)
#pragma unroll
    for (int nf = 0; nf < 4; ++nf)
#pragma unroll
      for (int i = 0; i < 4; ++i) {
        const int m = m0 + wm * 64 + mf * 16 + ((l >> 4) << 2) + i;
        const int o = n0 + wn * 64 + nf * 16 + (l & 15);
        const float val = acc[mf][nf][i];
        if (z == 0) {
          qbf[(size_t)m * kC + o] = f2h(val);
        } else {
          const int p = m - bb * kHW;
          const int y = p / kW, x = p - (p / kW) * kW;
          pd[((size_t)(bb * 8 + (o >> 5)) * kPP + (y + 3) * kPW + (x + 3)) *
                 32 +
             (o & 31)] = f2h(val);
        }
      }
}

// ---------------------------------------------------------------------------
// FC GEMM: A = Wfc (M=64 o-rows), B = att (N=128 pixels). C cols map to
// pixels -> fp32 stores/residual reads are 16-lane contiguous.
// ---------------------------------------------------------------------------
__global__ __launch_bounds__(256) void gemm_fc_kernel(
    const u16* __restrict__ att, const float* __restrict__ Wfc,
    const float* __restrict__ Res, float* __restrict__ Out) {
  __shared__ __align__(16) u16 As[64 * 64];   // Wfc rows (o)
  __shared__ __align__(16) u16 Bs[128 * 64];  // att rows (pixels)
  const int t = threadIdx.x;
  const int q0 = blockIdx.x * 128;  // pixel block (global over 4608)
  const int o0 = blockIdx.y * 64;
  const int bb = q0 / kHW, p0 = q0 - bb * kHW;  // 2304%128==0
  const int l = t & 63, w = t >> 6;

  f32x4 acc[4][2];
#pragma unroll
  for (int mf = 0; mf < 4; ++mf)
#pragma unroll
    for (int nf = 0; nf < 2; ++nf) acc[mf][nf] = (f32x4){0.f, 0.f, 0.f, 0.f};

  for (int kt = 0; kt < 4; ++kt) {
    const int k0 = kt * 64;
    if (kt) __syncthreads();
#pragma unroll
    for (int j = 0; j < 4; ++j) {  // As <- Wfc (cvt): 64 rows x 16 float4
      const int task = t + j * 256;
      const int rr = task >> 4, f4i = task & 15;
      const float4 val =
          *(const float4*)&Wfc[(size_t)(o0 + rr) * kC + k0 + f4i * 4];
      uint2 pk;
      pk.x = pack2h(val.x, val.y);
      pk.y = pack2h(val.z, val.w);
      const int bo = (f4i * 8) ^ ((rr & 7) << 4);
      *(uint2*)&As[rr * 64 + (bo >> 1)] = pk;
    }
#pragma unroll
    for (int j = 0; j < 4; ++j) {  // Bs <- att (f16): 128 rows x 8 uint4
      const int task = t + j * 256;
      const int rr = task >> 3, ch = task & 7;
      const uint4 val =
          *(const uint4*)&att[(size_t)(q0 + rr) * kC + k0 + ch * 8];
      const int bo = (ch * 16) ^ ((rr & 7) << 4);
      *(uint4*)&Bs[rr * 64 + (bo >> 1)] = val;
    }
    __syncthreads();
#pragma unroll
    for (int ks = 0; ks < 2; ++ks) {
      const int bo = ks * 64 + ((l >> 4) << 4);
      f16x8 a[4], bfr[2];
#pragma unroll
      for (int mf = 0; mf < 4; ++mf) {
        const int row = mf * 16 + (l & 15);
        a[mf] = *(const f16x8*)&As[row * 64 + ((bo ^ ((row & 7) << 4)) >> 1)];
      }
#pragma unroll
      for (int nf = 0; nf < 2; ++nf) {
        const int row = w * 32 + nf * 16 + (l & 15);
        bfr[nf] =
            *(const f16x8*)&Bs[row * 64 + ((bo ^ ((row & 7) << 4)) >> 1)];
      }
#pragma unroll
      for (int mf = 0; mf < 4; ++mf)
#pragma unroll
        for (int nf = 0; nf < 2; ++nf)
          acc[mf][nf] = __builtin_amdgcn_mfma_f32_16x16x32_f16(
              a[mf], bfr[nf], acc[mf][nf], 0, 0, 0);
    }
  }
#pragma unroll
  for (int mf = 0; mf < 4; ++mf)
#pragma unroll
    for (int nf = 0; nf < 2; ++nf)
#pragma unroll
      for (int i = 0; i < 4; ++i) {
        const int o = o0 + mf * 16 + ((l >> 4) << 2) + i;
        const int p = p0 + w * 32 + nf * 16 + (l & 15);
        const size_t addr = ((size_t)(bb * kC + o)) * kHW + p;
        Out[addr] = acc[mf][nf][i] + Res[addr];
      }
}

// ---------------------------------------------------------------------------
// Local 7x7 attention. Block = 256 thr (4 waves) = one (b,h) 8x8 tile.
// 4 lanes per pixel split the 49 neighbors (n % 4 == lane>>4).
// f16 data; MACs promote f16->f32 (v_fma_mix_f32).
// ---------------------------------------------------------------------------
__device__ __forceinline__ void dot8(float& d, uint4 r, const float* qf) {
  const f16x8 h = __builtin_bit_cast(f16x8, r);
#pragma unroll
  for (int j = 0; j < 8; ++j) d += (float)h[j] * qf[j];
}
__device__ __forceinline__ void pv8(float* of, uint4 r, float e) {
  const f16x8 h = __builtin_bit_cast(f16x8, r);
#pragma unroll
  for (int j = 0; j < 8; ++j) of[j] += e * (float)h[j];
}

__global__ __launch_bounds__(256) void attn2_kernel(
    const u16* __restrict__ qbf, const u16* __restrict__ kpad,
    const u16* __restrict__ vpad, u16* __restrict__ att) {
  __shared__ __align__(16) u16 ks_[196 * 40];
  __shared__ __align__(16) u16 vs_[196 * 40];
  const int t = threadIdx.x;
  const int tile = blockIdx.x, bh = blockIdx.y;
  const int byy = tile / 6, bxx = tile % 6;
  const int b = bh >> 3, h = bh & 7;
  const int l = t & 63, w = t >> 6;
  const int pi = w * 16 + (l & 15);
  const int ty = pi >> 3, tx = pi & 7;
  const int ng = l >> 4;
  const int gp = (byy * 8 + ty) * kW + (bxx * 8 + tx);

  const size_t qbase = ((size_t)(b * kHW + gp)) * kC + h * 32;
  float qf[32];
#pragma unroll
  for (int c8 = 0; c8 < 4; ++c8) {
    const uint4 qq = *(const uint4*)&qbf[qbase + c8 * 8];
    const f16x8 hh = __builtin_bit_cast(f16x8, qq);
#pragma unroll
    for (int j = 0; j < 8; ++j) qf[c8 * 8 + j] = (float)hh[j];
  }

  const size_t kvbase = (size_t)bh * kPP * 32;
  for (int task = t; task < 1568; task += 256) {
    const int mat = task >= 784;
    const int rem = task - mat * 784;
    const int hp = rem >> 2, ch = rem & 3;
    const int hy = hp / 14, hx = hp - hy * 14;
    const size_t src =
        kvbase + ((size_t)((byy * 8 + hy) * kPW + (bxx * 8 + hx))) * 32 +
        ch * 8;
    const uint4 val = *(const uint4*)&(mat ? vpad : kpad)[src];
    u16* dst = mat ? vs_ : ks_;
    *(uint4*)&dst[hp * 40 + ch * 8] = val;
  }
  __syncthreads();

  float s[13];
  float pm = -1e30f;
#pragma unroll
  for (int nn = 0; nn < 13; ++nn) {
    const int n = nn * 4 + ng;
    float sc = -1e30f;
    if (n < 49) {
      const int ky = n / 7, kx = n - ky * 7;
      const int pp = (ty + ky) * 14 + (tx + kx);
      const u16* kr = &ks_[pp * 40];
      float d = 0.f;
      dot8(d, *(const uint4*)&kr[0], qf + 0);
      dot8(d, *(const uint4*)&kr[8], qf + 8);
      dot8(d, *(const uint4*)&kr[16], qf + 16);
      dot8(d, *(const uint4*)&kr[24], qf + 24);
      sc = d * kInvTemp;
    }
    s[nn] = sc;
    pm = fmaxf(pm, sc);
  }
  pm = fmaxf(pm, __shfl_xor(pm, 16));
  pm = fmaxf(pm, __shfl_xor(pm, 32));
  float zs = 0.f;
#pragma unroll
  for (int nn = 0; nn < 13; ++nn) {
    const float e = __expf(s[nn] - pm);  // masked lanes: exp(-huge) = 0
    s[nn] = e;
    zs += e;
  }
  zs += __shfl_xor(zs, 16);
  zs += __shfl_xor(zs, 32);
  const float rinv = 1.0f / zs;

  float of[32];
#pragma unroll
  for (int d = 0; d < 32; ++d) of[d] = 0.f;
#pragma unroll
  for (int nn = 0; nn < 13; ++nn) {
    const int n = nn * 4 + ng;
    if (n < 49) {
      const int ky = n / 7, kx = n - ky * 7;
      const int pp = (ty + ky) * 14 + (tx + kx);
      const u16* vr = &vs_[pp * 40];
      const float e = s[nn];
      pv8(of + 0, *(const uint4*)&vr[0], e);
      pv8(of + 8, *(const uint4*)&vr[8], e);
      pv8(of + 16, *(const uint4*)&vr[16], e);
      pv8(of + 24, *(const uint4*)&vr[24], e);
    }
  }
#pragma unroll
  for (int d = 0; d < 32; ++d) {
    of[d] += __shfl_xor(of[d], 16);
    of[d] += __shfl_xor(of[d], 32);
  }
  float seg[8];
#pragma unroll
  for (int j = 0; j < 8; ++j) {
    const float a01 = (ng == 0) ? of[j] : of[8 + j];
    const float a23 = (ng == 2) ? of[16 + j] : of[24 + j];
    seg[j] = (ng < 2) ? a01 : a23;
  }
  uint4 outv;
  outv.x = pack2h(seg[0] * rinv, seg[1] * rinv);
  outv.y = pack2h(seg[2] * rinv, seg[3] * rinv);
  outv.z = pack2h(seg[4] * rinv, seg[5] * rinv);
  outv.w = pack2h(seg[6] * rinv, seg[7] * rinv);
  *(uint4*)&att[((size_t)(b * kHW + gp)) * kC + h * 32 + ng * 8] = outv;
}

}  // namespace

extern "C" void kernel_launch(void* const* d_in, const int* in_sizes, int n_in,
                              void* d_out, int out_size, void* d_ws,
                              size_t ws_size, hipStream_t stream) {
  const float* q = (const float*)d_in[0];
  const float* k = (const float*)d_in[1];
  const float* v = (const float*)d_in[2];
  const float* Wq = (const float*)d_in[3];
  const float* Wk = (const float*)d_in[4];
  const float* Wv = (const float*)d_in[5];
  const float* Wfc = (const float*)d_in[6];
  float* out = (float*)d_out;

  u16* ws16 = (u16*)d_ws;
  u16* kpad = ws16;
  u16* vpad = ws16 + KPAD_U16;
  u16* qbf = ws16 + 2 * KPAD_U16;
  u16* att = qbf + QBF_U16;

  gemm_qkv_kernel<<<dim3(kM / 128, kC / 128, 3), 256, 0, stream>>>(
      q, k, v, Wq, Wk, Wv, qbf, kpad, vpad);

  attn2_kernel<<<dim3(36, 16), 256, 0, stream>>>(qbf, kpad, vpad, att);

  gemm_fc_kernel<<<dim3(kM / 128, kC / 64), 256, 0, stream>>>(att, Wfc, q,
                                                              out);
}

// Round 7
// 50.006 us; speedup vs baseline: 1.2300x; 1.2300x over previous
//
#include <hip/hip_runtime.h>

typedef unsigned int u32;
typedef unsigned short u16;
typedef __attribute__((ext_vector_type(8))) _Float16 f16x8;
typedef __attribute__((ext_vector_type(4))) float f32x4;

namespace {

constexpr int kH = 48, kW = 48, kHW = kH * kW;     // 2304
constexpr int kC = 256;
constexpr int kB = 2;
constexpr int kM = kB * kHW;                        // 4608 GEMM rows
constexpr int kPH = 54, kPW = 56, kPP = kPH * kPW;  // padded kv grid (3024)
constexpr float kInvTemp = 0.17677669529663687f;    // 1/sqrt(32)

constexpr size_t KPAD_U16 = (size_t)16 * kPP * 32;  // 1,548,288 u16 per mat
constexpr size_t QBF_U16 = (size_t)kM * kC;         // 1,179,648 u16
// border zeroing: 720 border pixels/plane x 16 planes x 2 mats x 4 uint4
constexpr int kZeroTasks = 720 * 16 * 2 * 4;        // 92,160
constexpr int kZeroPerBlk = 54;                     // 1728 qkv blocks x 54 >= 92160

// 1-instruction f32x2 -> f16x2 pack (v_cvt_pkrtz_f16_f32)
__device__ __forceinline__ u32 pack2h(float lo, float hi) {
  return __builtin_bit_cast(u32, __builtin_amdgcn_cvt_pkrtz(lo, hi));
}
__device__ __forceinline__ u16 f2h(float f) {
  return __builtin_bit_cast(u16, (_Float16)f);
}
__device__ __forceinline__ float f4e(const float4 v, int i) {
  return (i == 0) ? v.x : (i == 1) ? v.y : (i == 2) ? v.z : v.w;
}

// ---------------------------------------------------------------------------
// Fused QKV GEMM, 32x64 tiles -> 1728 blocks (27 waves/CU; latency-bound op).
// A staged directly from fp32 [b][c][p] (register 4x2 transpose + pkrtz).
// z=0: q -> f16 [m][256].  z=1/2: k/v -> zero-padded f16 [bh][54*56][32].
// Also zeroes the pad borders (disjoint from interior epilogue writes).
// ---------------------------------------------------------------------------
__global__ __launch_bounds__(256) void gemm_qkv_kernel(
    const float* __restrict__ q, const float* __restrict__ k,
    const float* __restrict__ v, const float* __restrict__ Wq,
    const float* __restrict__ Wk, const float* __restrict__ Wv,
    u16* __restrict__ qbf, u16* __restrict__ kpad, u16* __restrict__ vpad) {
  __shared__ __align__(16) u16 As[32 * 64];
  __shared__ __align__(16) u16 Bs[64 * 64];
  const int t = threadIdx.x;

  // ---- border zeroing (1.5 MB total across the 1728 blocks) ----
  {
    const int bid = (blockIdx.z * 4 + blockIdx.y) * 144 + blockIdx.x;
    const int T = bid * kZeroPerBlk + t;
    if (t < kZeroPerBlk && T < kZeroTasks) {
      const int ch = T & 3, rest = T >> 2;  // rest < 23040
      const int pm = rest / 720, bi = rest - pm * 720;
      int y, x;
      if (bi < 336) {  // full rows 0,1,2,51,52,53
        const int r = bi / 56, c = bi - (bi / 56) * 56;
        y = (r < 3) ? r : 48 + r;
        x = c;
      } else {  // rows 3..50, cols {0,1,2,51..55}
        const int r = (bi - 336) >> 3, c = (bi - 336) & 7;
        y = 3 + r;
        x = (c < 3) ? c : c + 48;
      }
      u16* pb = (pm >= 16) ? vpad : kpad;
      const uint4 zz = {0u, 0u, 0u, 0u};
      *(uint4*)&pb[((size_t)(pm & 15) * kPP + y * kPW + x) * 32 + ch * 8] = zz;
    }
  }

  const int z = blockIdx.z;
  const float* X = (z == 0) ? q : (z == 1) ? k : v;
  const float* Wm = (z == 0) ? Wq : (z == 1) ? Wk : Wv;
  const int m0 = blockIdx.x * 32, n0 = blockIdx.y * 64;
  const int bb = m0 / kHW, p0 = m0 - bb * kHW;  // 2304%32==0: no straddle
  const int l = t & 63, w = t >> 6, wm = w >> 1, wn = w & 1;
  const int mq = t & 7, kp = t >> 3;  // kp in [0,32): c-pair index

  f32x4 acc[2];
#pragma unroll
  for (int nf = 0; nf < 2; ++nf) acc[nf] = (f32x4){0.f, 0.f, 0.f, 0.f};

  for (int kt = 0; kt < 4; ++kt) {
    const int k0 = kt * 64;
    if (kt) __syncthreads();
    // A stage: 2 coalesced c-row float4 reads, 4x2 register transpose,
    // pkrtz pack, 4B swizzled LDS writes.
    {
      const float* ab =
          X + ((size_t)(bb * kC + k0 + kp * 2)) * kHW + p0 + mq * 4;
      const float4 r0 = *(const float4*)(ab);
      const float4 r1 = *(const float4*)(ab + kHW);
#pragma unroll
      for (int i = 0; i < 4; ++i) {
        const int ml = mq * 4 + i;
        const u32 pk = pack2h(f4e(r0, i), f4e(r1, i));
        const int bo = (kp * 4) ^ ((ml & 7) << 4);
        *(u32*)&As[ml * 64 + (bo >> 1)] = pk;
      }
    }
    // B stage: fp32 W[o][c] -> f16, same swizzle (64 rows x 16 float4)
#pragma unroll
    for (int j = 0; j < 4; ++j) {
      const int task = t + j * 256;
      const int rr = task >> 4, f4i = task & 15;
      const float4 val =
          *(const float4*)&Wm[(size_t)(n0 + rr) * kC + k0 + f4i * 4];
      uint2 pk;
      pk.x = pack2h(val.x, val.y);
      pk.y = pack2h(val.z, val.w);
      const int bo = (f4i * 8) ^ ((rr & 7) << 4);
      *(uint2*)&Bs[rr * 64 + (bo >> 1)] = pk;
    }
    __syncthreads();
#pragma unroll
    for (int ks = 0; ks < 2; ++ks) {
      const int bo = ks * 64 + ((l >> 4) << 4);
      const int rowa = wm * 16 + (l & 15);
      const f16x8 a =
          *(const f16x8*)&As[rowa * 64 + ((bo ^ ((rowa & 7) << 4)) >> 1)];
      f16x8 bfr[2];
#pragma unroll
      for (int nf = 0; nf < 2; ++nf) {
        const int row = wn * 32 + nf * 16 + (l & 15);
        bfr[nf] =
            *(const f16x8*)&Bs[row * 64 + ((bo ^ ((row & 7) << 4)) >> 1)];
      }
#pragma unroll
      for (int nf = 0; nf < 2; ++nf)
        acc[nf] = __builtin_amdgcn_mfma_f32_16x16x32_f16(a, bfr[nf], acc[nf],
                                                         0, 0, 0);
    }
  }

  u16* pd = (z == 1) ? kpad : vpad;
#pragma unroll
  for (int nf = 0; nf < 2; ++nf)
#pragma unroll
    for (int i = 0; i < 4; ++i) {
      const int m = m0 + wm * 16 + ((l >> 4) << 2) + i;
      const int o = n0 + wn * 32 + nf * 16 + (l & 15);
      const float val = acc[nf][i];
      if (z == 0) {
        qbf[(size_t)m * kC + o] = f2h(val);
      } else {
        const int p = m - bb * kHW;
        const int y = p / kW, x = p - (p / kW) * kW;
        pd[((size_t)(bb * 8 + (o >> 5)) * kPP + (y + 3) * kPW + (x + 3)) * 32 +
           (o & 31)] = f2h(val);
      }
    }
}

// ---------------------------------------------------------------------------
// FC GEMM: A = Wfc (M=32 o-rows), B = att (N=64 pixels) -> 576 blocks
// (9 waves/CU). C cols map to pixels -> fp32 stores/residual 16-lane contig.
// ---------------------------------------------------------------------------
__global__ __launch_bounds__(256) void gemm_fc_kernel(
    const u16* __restrict__ att, const float* __restrict__ Wfc,
    const float* __restrict__ Res, float* __restrict__ Out) {
  __shared__ __align__(16) u16 As[32 * 64];  // Wfc rows (o)
  __shared__ __align__(16) u16 Bs[64 * 64];  // att rows (pixels)
  const int t = threadIdx.x;
  const int q0 = blockIdx.x * 64;  // pixel block (global over 4608)
  const int o0 = blockIdx.y * 32;
  const int bb = q0 / kHW, p0 = q0 - bb * kHW;  // 2304%64==0
  const int l = t & 63, w = t >> 6, wm = w >> 1, wn = w & 1;

  f32x4 acc[2];
#pragma unroll
  for (int nf = 0; nf < 2; ++nf) acc[nf] = (f32x4){0.f, 0.f, 0.f, 0.f};

  for (int kt = 0; kt < 4; ++kt) {
    const int k0 = kt * 64;
    if (kt) __syncthreads();
#pragma unroll
    for (int j = 0; j < 2; ++j) {  // As <- Wfc (cvt): 32 rows x 16 float4
      const int task = t + j * 256;
      const int rr = task >> 4, f4i = task & 15;
      const float4 val =
          *(const float4*)&Wfc[(size_t)(o0 + rr) * kC + k0 + f4i * 4];
      uint2 pk;
      pk.x = pack2h(val.x, val.y);
      pk.y = pack2h(val.z, val.w);
      const int bo = (f4i * 8) ^ ((rr & 7) << 4);
      *(uint2*)&As[rr * 64 + (bo >> 1)] = pk;
    }
#pragma unroll
    for (int j = 0; j < 2; ++j) {  // Bs <- att (f16): 64 rows x 8 uint4
      const int task = t + j * 256;
      const int rr = task >> 3, ch = task & 7;
      const uint4 val =
          *(const uint4*)&att[(size_t)(q0 + rr) * kC + k0 + ch * 8];
      const int bo = (ch * 16) ^ ((rr & 7) << 4);
      *(uint4*)&Bs[rr * 64 + (bo >> 1)] = val;
    }
    __syncthreads();
#pragma unroll
    for (int ks = 0; ks < 2; ++ks) {
      const int bo = ks * 64 + ((l >> 4) << 4);
      const int rowa = wm * 16 + (l & 15);
      const f16x8 a =
          *(const f16x8*)&As[rowa * 64 + ((bo ^ ((rowa & 7) << 4)) >> 1)];
      f16x8 bfr[2];
#pragma unroll
      for (int nf = 0; nf < 2; ++nf) {
        const int row = wn * 32 + nf * 16 + (l & 15);
        bfr[nf] =
            *(const f16x8*)&Bs[row * 64 + ((bo ^ ((row & 7) << 4)) >> 1)];
      }
#pragma unroll
      for (int nf = 0; nf < 2; ++nf)
        acc[nf] = __builtin_amdgcn_mfma_f32_16x16x32_f16(a, bfr[nf], acc[nf],
                                                         0, 0, 0);
    }
  }
#pragma unroll
  for (int nf = 0; nf < 2; ++nf)
#pragma unroll
    for (int i = 0; i < 4; ++i) {
      const int o = o0 + wm * 16 + ((l >> 4) << 2) + i;
      const int p = p0 + wn * 32 + nf * 16 + (l & 15);
      const size_t addr = ((size_t)(bb * kC + o)) * kHW + p;
      Out[addr] = acc[nf][i] + Res[addr];
    }
}

// ---------------------------------------------------------------------------
// Local 7x7 attention. Block = 256 thr (4 waves) = one (b,h) 8x8 tile.
// 4 lanes per pixel split the 49 neighbors (n % 4 == lane>>4).
// f16 data; MACs promote f16->f32 (v_fma_mix_f32).
// ---------------------------------------------------------------------------
__device__ __forceinline__ void dot8(float& d, uint4 r, const float* qf) {
  const f16x8 h = __builtin_bit_cast(f16x8, r);
#pragma unroll
  for (int j = 0; j < 8; ++j) d += (float)h[j] * qf[j];
}
__device__ __forceinline__ void pv8(float* of, uint4 r, float e) {
  const f16x8 h = __builtin_bit_cast(f16x8, r);
#pragma unroll
  for (int j = 0; j < 8; ++j) of[j] += e * (float)h[j];
}

__global__ __launch_bounds__(256) void attn2_kernel(
    const u16* __restrict__ qbf, const u16* __restrict__ kpad,
    const u16* __restrict__ vpad, u16* __restrict__ att) {
  __shared__ __align__(16) u16 ks_[196 * 40];
  __shared__ __align__(16) u16 vs_[196 * 40];
  const int t = threadIdx.x;
  const int tile = blockIdx.x, bh = blockIdx.y;
  const int byy = tile / 6, bxx = tile % 6;
  const int b = bh >> 3, h = bh & 7;
  const int l = t & 63, w = t >> 6;
  const int pi = w * 16 + (l & 15);
  const int ty = pi >> 3, tx = pi & 7;
  const int ng = l >> 4;
  const int gp = (byy * 8 + ty) * kW + (bxx * 8 + tx);

  const size_t qbase = ((size_t)(b * kHW + gp)) * kC + h * 32;
  float qf[32];
#pragma unroll
  for (int c8 = 0; c8 < 4; ++c8) {
    const uint4 qq = *(const uint4*)&qbf[qbase + c8 * 8];
    const f16x8 hh = __builtin_bit_cast(f16x8, qq);
#pragma unroll
    for (int j = 0; j < 8; ++j) qf[c8 * 8 + j] = (float)hh[j];
  }

  const size_t kvbase = (size_t)bh * kPP * 32;
  for (int task = t; task < 1568; task += 256) {
    const int mat = task >= 784;
    const int rem = task - mat * 784;
    const int hp = rem >> 2, ch = rem & 3;
    const int hy = hp / 14, hx = hp - hy * 14;
    const size_t src =
        kvbase + ((size_t)((byy * 8 + hy) * kPW + (bxx * 8 + hx))) * 32 +
        ch * 8;
    const uint4 val = *(const uint4*)&(mat ? vpad : kpad)[src];
    u16* dst = mat ? vs_ : ks_;
    *(uint4*)&dst[hp * 40 + ch * 8] = val;
  }
  __syncthreads();

  float s[13];
  float pm = -1e30f;
#pragma unroll
  for (int nn = 0; nn < 13; ++nn) {
    const int n = nn * 4 + ng;
    float sc = -1e30f;
    if (n < 49) {
      const int ky = n / 7, kx = n - ky * 7;
      const int pp = (ty + ky) * 14 + (tx + kx);
      const u16* kr = &ks_[pp * 40];
      float d = 0.f;
      dot8(d, *(const uint4*)&kr[0], qf + 0);
      dot8(d, *(const uint4*)&kr[8], qf + 8);
      dot8(d, *(const uint4*)&kr[16], qf + 16);
      dot8(d, *(const uint4*)&kr[24], qf + 24);
      sc = d * kInvTemp;
    }
    s[nn] = sc;
    pm = fmaxf(pm, sc);
  }
  pm = fmaxf(pm, __shfl_xor(pm, 16));
  pm = fmaxf(pm, __shfl_xor(pm, 32));
  float zs = 0.f;
#pragma unroll
  for (int nn = 0; nn < 13; ++nn) {
    const float e = __expf(s[nn] - pm);  // masked lanes: exp(-huge) = 0
    s[nn] = e;
    zs += e;
  }
  zs += __shfl_xor(zs, 16);
  zs += __shfl_xor(zs, 32);
  const float rinv = 1.0f / zs;

  float of[32];
#pragma unroll
  for (int d = 0; d < 32; ++d) of[d] = 0.f;
#pragma unroll
  for (int nn = 0; nn < 13; ++nn) {
    const int n = nn * 4 + ng;
    if (n < 49) {
      const int ky = n / 7, kx = n - ky * 7;
      const int pp = (ty + ky) * 14 + (tx + kx);
      const u16* vr = &vs_[pp * 40];
      const float e = s[nn];
      pv8(of + 0, *(const uint4*)&vr[0], e);
      pv8(of + 8, *(const uint4*)&vr[8], e);
      pv8(of + 16, *(const uint4*)&vr[16], e);
      pv8(of + 24, *(const uint4*)&vr[24], e);
    }
  }
#pragma unroll
  for (int d = 0; d < 32; ++d) {
    of[d] += __shfl_xor(of[d], 16);
    of[d] += __shfl_xor(of[d], 32);
  }
  float seg[8];
#pragma unroll
  for (int j = 0; j < 8; ++j) {
    const float a01 = (ng == 0) ? of[j] : of[8 + j];
    const float a23 = (ng == 2) ? of[16 + j] : of[24 + j];
    seg[j] = (ng < 2) ? a01 : a23;
  }
  uint4 outv;
  outv.x = pack2h(seg[0] * rinv, seg[1] * rinv);
  outv.y = pack2h(seg[2] * rinv, seg[3] * rinv);
  outv.z = pack2h(seg[4] * rinv, seg[5] * rinv);
  outv.w = pack2h(seg[6] * rinv, seg[7] * rinv);
  *(uint4*)&att[((size_t)(b * kHW + gp)) * kC + h * 32 + ng * 8] = outv;
}

}  // namespace

extern "C" void kernel_launch(void* const* d_in, const int* in_sizes, int n_in,
                              void* d_out, int out_size, void* d_ws,
                              size_t ws_size, hipStream_t stream) {
  const float* q = (const float*)d_in[0];
  const float* k = (const float*)d_in[1];
  const float* v = (const float*)d_in[2];
  const float* Wq = (const float*)d_in[3];
  const float* Wk = (const float*)d_in[4];
  const float* Wv = (const float*)d_in[5];
  const float* Wfc = (const float*)d_in[6];
  float* out = (float*)d_out;

  u16* ws16 = (u16*)d_ws;
  u16* kpad = ws16;
  u16* vpad = ws16 + KPAD_U16;
  u16* qbf = ws16 + 2 * KPAD_U16;
  u16* att = qbf + QBF_U16;

  gemm_qkv_kernel<<<dim3(kM / 32, kC / 64, 3), 256, 0, stream>>>(
      q, k, v, Wq, Wk, Wv, qbf, kpad, vpad);

  attn2_kernel<<<dim3(36, 16), 256, 0, stream>>>(qbf, kpad, vpad, att);

  gemm_fc_kernel<<<dim3(kM / 64, kC / 32), 256, 0, stream>>>(att, Wfc, q, out);
}